// Round 13
// baseline (494.581 us; speedup 1.0000x reference)
//
#include <hip/hip_runtime.h>
#include <hip/hip_bf16.h>
#include <math.h>

#define NN   50000
#define NE   400000
#define NE2  (2*NE + NN)      // 850000 edges after symmetrize + self loops
#define DIM  256
#define NH   8
#define NM   (NN*DIM)         // 12,800,000 elements per activation buffer
#define NBLK 196              // ceil(NN/256) blocks for scan
#define MPAD 50048            // 782*64, padded row count for bf16 activations

typedef __attribute__((ext_vector_type(8))) short bf16x8;
typedef __attribute__((ext_vector_type(8))) unsigned short u16x8;
typedef __attribute__((ext_vector_type(4))) float f32x4;

#define GLOAD16(g, l) __builtin_amdgcn_global_load_lds( \
    (const __attribute__((address_space(1))) void*)(g), \
    (__attribute__((address_space(3))) void*)(l), 16, 0, 0)

__device__ __forceinline__ float b2f(unsigned short u) {
    unsigned int i = ((unsigned int)u) << 16;
    float f; __builtin_memcpy(&f, &i, 4); return f;
}
__device__ __forceinline__ unsigned short f2b(float f) {
    __hip_bfloat16 h = __float2bfloat16(f);
    unsigned short u; __builtin_memcpy(&u, &h, 2); return u;
}

// --------------------------------------------- fused wide bf16 MFMA GEMM
// Cb[MPAD,256] = T(A)[MPAD,256] @ Bt[256,256]^T + bias, bf16 out, unguarded.
// MODE 0: A = fp32 x (raw in LDS), T = bf16 cast at fragment read.
// MODE 1: A = bf16 raw aggregate (raw in LDS), T = BN+ReLU at fragment read.
// Epilogue fuses per-head attention factors (el/er) via l15-shuffle reduce.
// 64-row tile, 256 thr = 4 waves (col slices); 782 blocks = 3.05/CU balance.
template<int MODE>
__global__ __launch_bounds__(256) void gemm_wide(
    const float* __restrict__ Af, const unsigned short* __restrict__ Ab16,
    const unsigned short* __restrict__ Bt, const float* __restrict__ bias,
    const float* __restrict__ sums, const float* __restrict__ g,
    const float* __restrict__ be, const float* __restrict__ a_l,
    const float* __restrict__ a_r, float* __restrict__ el,
    float* __restrict__ er, unsigned short* __restrict__ Cb)
{
    __shared__ char  ldsA[(MODE == 0) ? 8192 : 4096];  // raw A, chunk-major
    __shared__ short ldsB[4][256][8];                   // 16 KiB
    __shared__ float scL[256], shL[256];
    const int tid  = threadIdx.x;
    const int wave = tid >> 6, lane = tid & 63;
    const int wc = wave;                 // 4 col slices of 64
    const int l15 = lane & 15, lk = lane >> 4;
    const int row0 = blockIdx.x * 64;

    if (MODE == 1) {
        float mean = sums[tid] * (1.f / NN);
        float var  = sums[256 + tid] * (1.f / NN) - mean * mean;
        float s    = g[tid] * rsqrtf(var + 1e-5f);
        scL[tid] = s;
        shL[tid] = be[tid] - mean * s;
        __syncthreads();
    }

    f32x4 acc[4][4] = {};
    for (int t = 0; t < 8; ++t) {
        const int k0 = t * 32;
        if (t) __syncthreads();                       // prior reads done
        // ---- A stage: raw global->LDS, chunk-major (seg = p*64 + r)
        if (MODE == 0) {
            #pragma unroll
            for (int c = 0; c < 2; ++c) {
                int seg = c * 256 + tid;              // 0..511
                int p = seg >> 6, r = seg & 63;       // p = 4-float chunk
                int rowg = min(row0 + r, NN - 1);     // clamp: x has NN rows
                GLOAD16(Af + (size_t)rowg * 256 + k0 + p * 4,
                        ldsA + (size_t)seg * 16);
            }
        } else {
            int ch = tid >> 6, r = tid & 63;          // 256 segs of 16B
            GLOAD16(Ab16 + (size_t)(row0 + r) * 256 + k0 + ch * 8,
                    ldsA + (size_t)tid * 16);
        }
        // ---- B stage: full 256 cols
        #pragma unroll
        for (int c = 0; c < 4; ++c) {
            int seg = c * 256 + tid;                  // 0..1023
            int bch = seg >> 8, br = seg & 255;
            GLOAD16(Bt + (size_t)br * 256 + k0 + bch * 8, &ldsB[bch][br][0]);
        }
        __syncthreads();                              // drains vmcnt+lgkm
        // ---- fragments (+ transform) + MFMA
        bf16x8 af[4], bf[4];
        #pragma unroll
        for (int m = 0; m < 4; ++m) {
            int r = m * 16 + l15;
            if (MODE == 0) {
                float4 v0 = *reinterpret_cast<const float4*>(
                    ldsA + (size_t)(2 * lk) * 1024 + (size_t)r * 16);
                float4 v1 = *reinterpret_cast<const float4*>(
                    ldsA + (size_t)(2 * lk + 1) * 1024 + (size_t)r * 16);
                bf16x8 o;
                o[0]=(short)f2b(v0.x); o[1]=(short)f2b(v0.y);
                o[2]=(short)f2b(v0.z); o[3]=(short)f2b(v0.w);
                o[4]=(short)f2b(v1.x); o[5]=(short)f2b(v1.y);
                o[6]=(short)f2b(v1.z); o[7]=(short)f2b(v1.w);
                af[m] = o;
            } else {
                u16x8 rw = *reinterpret_cast<const u16x8*>(
                    ldsA + (size_t)lk * 1024 + (size_t)r * 16);
                int kc = k0 + lk * 8;
                float4 s0 = *reinterpret_cast<const float4*>(&scL[kc]);
                float4 s1 = *reinterpret_cast<const float4*>(&scL[kc + 4]);
                float4 h0 = *reinterpret_cast<const float4*>(&shL[kc]);
                float4 h1 = *reinterpret_cast<const float4*>(&shL[kc + 4]);
                bf16x8 o;
                o[0]=(short)f2b(fmaxf(0.f, fmaf(b2f(rw[0]), s0.x, h0.x)));
                o[1]=(short)f2b(fmaxf(0.f, fmaf(b2f(rw[1]), s0.y, h0.y)));
                o[2]=(short)f2b(fmaxf(0.f, fmaf(b2f(rw[2]), s0.z, h0.z)));
                o[3]=(short)f2b(fmaxf(0.f, fmaf(b2f(rw[3]), s0.w, h0.w)));
                o[4]=(short)f2b(fmaxf(0.f, fmaf(b2f(rw[4]), s1.x, h1.x)));
                o[5]=(short)f2b(fmaxf(0.f, fmaf(b2f(rw[5]), s1.y, h1.y)));
                o[6]=(short)f2b(fmaxf(0.f, fmaf(b2f(rw[6]), s1.z, h1.z)));
                o[7]=(short)f2b(fmaxf(0.f, fmaf(b2f(rw[7]), s1.w, h1.w)));
                af[m] = o;
            }
        }
        #pragma unroll
        for (int n = 0; n < 4; ++n)
            bf[n] = *reinterpret_cast<const bf16x8*>(&ldsB[lk][wc*64 + n*16 + l15][0]);
        #pragma unroll
        for (int m = 0; m < 4; ++m)
            #pragma unroll
            for (int n = 0; n < 4; ++n)
                acc[m][n] = __builtin_amdgcn_mfma_f32_16x16x32_bf16(af[m], bf[n], acc[m][n], 0, 0, 0);
    }

    // ---- epilogue: C write + fused per-head score factors
    const int h0 = wc * 2;
    float bcol[4], alv[4], arv[4];
    #pragma unroll
    for (int n = 0; n < 4; ++n) {
        int col = wc * 64 + n * 16 + l15;
        bcol[n] = bias[col];
        alv[n]  = a_l[col];
        arv[n]  = a_r[col];
    }
    #pragma unroll
    for (int m = 0; m < 4; ++m) {
        #pragma unroll
        for (int q = 0; q < 4; ++q) {
            int row = row0 + m*16 + lk*4 + q;
            float v0 = acc[m][0][q] + bcol[0];
            float v1 = acc[m][1][q] + bcol[1];
            float v2 = acc[m][2][q] + bcol[2];
            float v3 = acc[m][3][q] + bcol[3];
            size_t base = (size_t)row * 256 + wc * 64 + l15;
            Cb[base + 0]  = f2b(v0);
            Cb[base + 16] = f2b(v1);
            Cb[base + 32] = f2b(v2);
            Cb[base + 48] = f2b(v3);
            // head h0 spans n=0,1; head h0+1 spans n=2,3
            float pl0 = v0 * alv[0] + v1 * alv[1];
            float pl1 = v2 * alv[2] + v3 * alv[3];
            float pr0 = v0 * arv[0] + v1 * arv[1];
            float pr1 = v2 * arv[2] + v3 * arv[3];
            #pragma unroll
            for (int o = 1; o < 16; o <<= 1) {
                pl0 += __shfl_xor(pl0, o, 64);
                pl1 += __shfl_xor(pl1, o, 64);
                pr0 += __shfl_xor(pr0, o, 64);
                pr1 += __shfl_xor(pr1, o, 64);
            }
            if (l15 == 0 && row < NN) {
                float2 elv = { expf(pl0), expf(pl1) };
                float2 erv = { expf(pr0), expf(pr1) };
                *reinterpret_cast<float2*>(&el[(size_t)row * NH + h0]) = elv;
                *reinterpret_cast<float2*>(&er[(size_t)row * NH + h0]) = erv;
            }
        }
    }
}

// ------------------------------------------- head GEMM: BN+ReLU at frag read
// C[NN,128] = BN2(A)[.,256] @ Wth[128,256]^T + bias, fp32 out, guarded.
// 64-row tile, 256 thr = 4 waves (2r x 2c), 782 blocks.
__global__ __launch_bounds__(256) void gemm_head(
    const unsigned short* __restrict__ Ab16, const unsigned short* __restrict__ Bt,
    const float* __restrict__ bias, const float* __restrict__ sums,
    const float* __restrict__ g, const float* __restrict__ be,
    float* __restrict__ C)
{
    __shared__ char  ldsA[4096];        // raw bf16 A, chunk-major
    __shared__ short ldsB[4][128][8];   // 8 KiB
    __shared__ float scL[256], shL[256];
    const int tid  = threadIdx.x;
    const int wave = tid >> 6, lane = tid & 63;
    const int wr = wave >> 1, wc = wave & 1;
    const int l15 = lane & 15, lk = lane >> 4;
    const int row0 = blockIdx.x * 64;

    {
        float mean = sums[tid] * (1.f / NN);
        float var  = sums[256 + tid] * (1.f / NN) - mean * mean;
        float s    = g[tid] * rsqrtf(var + 1e-5f);
        scL[tid] = s;
        shL[tid] = be[tid] - mean * s;
    }
    __syncthreads();

    f32x4 acc[2][4] = {};
    for (int t = 0; t < 8; ++t) {
        const int k0 = t * 32;
        if (t) __syncthreads();
        {   // A stage: 256 segs of 16B (chunk-major)
            int ch = tid >> 6, r = tid & 63;
            GLOAD16(Ab16 + (size_t)(row0 + r) * 256 + k0 + ch * 8,
                    ldsA + (size_t)tid * 16);
        }
        #pragma unroll
        for (int c = 0; c < 2; ++c) {   // B stage: 512 segs
            int seg = c * 256 + tid;
            int ch = seg >> 7, br = seg & 127;
            GLOAD16(Bt + (size_t)br * 256 + k0 + ch * 8, &ldsB[ch][br][0]);
        }
        __syncthreads();
        bf16x8 af[2], bf[4];
        #pragma unroll
        for (int m = 0; m < 2; ++m) {
            int r = wr * 32 + m * 16 + l15;
            u16x8 rw = *reinterpret_cast<const u16x8*>(
                ldsA + (size_t)lk * 1024 + (size_t)r * 16);
            int kc = k0 + lk * 8;
            float4 s0 = *reinterpret_cast<const float4*>(&scL[kc]);
            float4 s1 = *reinterpret_cast<const float4*>(&scL[kc + 4]);
            float4 h0 = *reinterpret_cast<const float4*>(&shL[kc]);
            float4 h1 = *reinterpret_cast<const float4*>(&shL[kc + 4]);
            bf16x8 o;
            o[0]=(short)f2b(fmaxf(0.f, fmaf(b2f(rw[0]), s0.x, h0.x)));
            o[1]=(short)f2b(fmaxf(0.f, fmaf(b2f(rw[1]), s0.y, h0.y)));
            o[2]=(short)f2b(fmaxf(0.f, fmaf(b2f(rw[2]), s0.z, h0.z)));
            o[3]=(short)f2b(fmaxf(0.f, fmaf(b2f(rw[3]), s0.w, h0.w)));
            o[4]=(short)f2b(fmaxf(0.f, fmaf(b2f(rw[4]), s1.x, h1.x)));
            o[5]=(short)f2b(fmaxf(0.f, fmaf(b2f(rw[5]), s1.y, h1.y)));
            o[6]=(short)f2b(fmaxf(0.f, fmaf(b2f(rw[6]), s1.z, h1.z)));
            o[7]=(short)f2b(fmaxf(0.f, fmaf(b2f(rw[7]), s1.w, h1.w)));
            af[m] = o;
        }
        #pragma unroll
        for (int n = 0; n < 4; ++n)
            bf[n] = *reinterpret_cast<const bf16x8*>(&ldsB[lk][wc*64 + n*16 + l15][0]);
        #pragma unroll
        for (int m = 0; m < 2; ++m)
            #pragma unroll
            for (int n = 0; n < 4; ++n)
                acc[m][n] = __builtin_amdgcn_mfma_f32_16x16x32_bf16(af[m], bf[n], acc[m][n], 0, 0, 0);
    }
    #pragma unroll
    for (int m = 0; m < 2; ++m) {
        #pragma unroll
        for (int n = 0; n < 4; ++n) {
            int col = wc*64 + n*16 + l15;
            float bv = bias[col];
            #pragma unroll
            for (int q = 0; q < 4; ++q) {
                int row = row0 + wr*32 + m*16 + lk*4 + q;
                if (row < NN) C[(size_t)row * 128 + col] = acc[m][n][q] + bv;
            }
        }
    }
}

// --------------------------------------------------------------- weight cast
__global__ __launch_bounds__(256) void cast_wt_all(
    const float* __restrict__ W1, const float* __restrict__ W2,
    const float* __restrict__ Wh, unsigned short* __restrict__ Wt1,
    unsigned short* __restrict__ Wt2, unsigned short* __restrict__ Wth)
{
    int i = blockIdx.x * 256 + threadIdx.x;   // 0..65535
    {
        int k = i >> 8, n = i & 255;          // W[256,256]
        Wt1[n * 256 + k] = f2b(W1[i]);
        Wt2[n * 256 + k] = f2b(W2[i]);
    }
    if (i < 256 * 128) {
        int k = i >> 7, n = i & 127;          // Wh[256,128]
        Wth[n * 256 + k] = f2b(Wh[i]);
    }
}

// edge decode: e2 in [0,NE): (ei0,ei1); [NE,2NE): reversed; [2NE,NE2): self
__device__ __forceinline__ void edge_sd(const int* __restrict__ ei, int e2,
                                        int& s, int& d)
{
    if (e2 < NE)          { s = ei[e2];      d = ei[e2 + NE]; }
    else if (e2 < 2 * NE) { s = ei[e2];      d = ei[e2 - NE]; }
    else                  { s = e2 - 2 * NE; d = s; }
}

// --------------------------------------------------------------- CSR build
__global__ __launch_bounds__(256) void deg_count(const int* __restrict__ ei,
                                                 int* __restrict__ deg)
{
    int e2 = blockIdx.x * 256 + threadIdx.x;
    if (e2 >= NE2) return;
    int s, d;
    edge_sd(ei, e2, s, d);
    atomicAdd(&deg[d], 1);
}

__global__ __launch_bounds__(256) void scan_block_sums(
    const int* __restrict__ deg, int* __restrict__ bsum)
{
    __shared__ int tmp[256];
    const int t = threadIdx.x;
    int i = blockIdx.x * 256 + t;
    tmp[t] = (i < NN) ? deg[i] : 0;
    __syncthreads();
    #pragma unroll
    for (int o = 128; o > 0; o >>= 1) {
        if (t < o) tmp[t] += tmp[t + o];
        __syncthreads();
    }
    if (t == 0) bsum[blockIdx.x] = tmp[0];
}

__global__ void scan_bsum(int* __restrict__ bsum)   // 1 block, 256 threads
{
    __shared__ int tmp[256];
    const int t = threadIdx.x;
    int v = (t < NBLK) ? bsum[t] : 0;
    tmp[t] = v;
    __syncthreads();
    #pragma unroll
    for (int o = 1; o < 256; o <<= 1) {
        int x = (t >= o) ? tmp[t - o] : 0;
        __syncthreads();
        tmp[t] += x;
        __syncthreads();
    }
    bsum[t] = tmp[t] - v;   // exclusive prefix of block sums
}

__global__ __launch_bounds__(256) void scan_write(
    const int* __restrict__ deg, const int* __restrict__ bsum,
    int* __restrict__ rowoff)
{
    __shared__ int tmp[256];
    const int t = threadIdx.x;
    int i = blockIdx.x * 256 + t;
    int v = (i < NN) ? deg[i] : 0;
    tmp[t] = v;
    __syncthreads();
    #pragma unroll
    for (int o = 1; o < 256; o <<= 1) {
        int x = (t >= o) ? tmp[t - o] : 0;
        __syncthreads();
        tmp[t] += x;
        __syncthreads();
    }
    if (i <= NN) rowoff[i] = bsum[blockIdx.x] + tmp[t] - v;
}

__global__ __launch_bounds__(256) void csr_fill(
    const int* __restrict__ ei, const int* __restrict__ rowoff,
    int* __restrict__ cursor, int* __restrict__ csr)
{
    int e2 = blockIdx.x * 256 + threadIdx.x;
    if (e2 >= NE2) return;
    int s, d;
    edge_sd(ei, e2, s, d);
    int pos = atomicAdd(&cursor[d], 1);
    csr[rowoff[d] + pos] = s;
}

// ------------------------- fused softmax + aggregation, no atomics, no expf
// out[d] = er[d]*sum(el[s]*H[s]) / (er[d]*sum(el[s]) + eps); unroll x4 (best).
__global__ __launch_bounds__(256) void gat_aggregate_csr_bf16(
    const int* __restrict__ csr, const int* __restrict__ rowoff,
    const unsigned short* __restrict__ Hb, const float* __restrict__ el,
    const float* __restrict__ er, unsigned short* __restrict__ outb)
{
    const int wid  = (blockIdx.x * 256 + threadIdx.x) >> 6;   // node id
    const int lane = threadIdx.x & 63;
    if (wid >= NN) return;
    const int h = lane >> 3;
    const int i0 = rowoff[wid], i1 = rowoff[wid + 1];
    const int c4 = lane * 4;

    float ax0 = 0.f, ay0 = 0.f, az0 = 0.f, aw0 = 0.f, den0 = 0.f;
    float ax1 = 0.f, ay1 = 0.f, az1 = 0.f, aw1 = 0.f, den1 = 0.f;

    int i = i0;
    for (; i + 4 <= i1; i += 4) {
        int s0 = csr[i + 0], s1 = csr[i + 1], s2 = csr[i + 2], s3 = csr[i + 3];
        float e0 = el[s0 * NH + h], e1 = el[s1 * NH + h];
        float e2 = el[s2 * NH + h], e3 = el[s3 * NH + h];
        ushort4 h0 = *reinterpret_cast<const ushort4*>(&Hb[(size_t)s0 * DIM + c4]);
        ushort4 h1 = *reinterpret_cast<const ushort4*>(&Hb[(size_t)s1 * DIM + c4]);
        ushort4 h2 = *reinterpret_cast<const ushort4*>(&Hb[(size_t)s2 * DIM + c4]);
        ushort4 h3 = *reinterpret_cast<const ushort4*>(&Hb[(size_t)s3 * DIM + c4]);
        ax0 = fmaf(b2f(h0.x), e0, ax0); ay0 = fmaf(b2f(h0.y), e0, ay0);
        az0 = fmaf(b2f(h0.z), e0, az0); aw0 = fmaf(b2f(h0.w), e0, aw0);
        den0 += e0;
        ax1 = fmaf(b2f(h1.x), e1, ax1); ay1 = fmaf(b2f(h1.y), e1, ay1);
        az1 = fmaf(b2f(h1.z), e1, az1); aw1 = fmaf(b2f(h1.w), e1, aw1);
        den1 += e1;
        ax0 = fmaf(b2f(h2.x), e2, ax0); ay0 = fmaf(b2f(h2.y), e2, ay0);
        az0 = fmaf(b2f(h2.z), e2, az0); aw0 = fmaf(b2f(h2.w), e2, aw0);
        den0 += e2;
        ax1 = fmaf(b2f(h3.x), e3, ax1); ay1 = fmaf(b2f(h3.y), e3, ay1);
        az1 = fmaf(b2f(h3.z), e3, az1); aw1 = fmaf(b2f(h3.w), e3, aw1);
        den1 += e3;
    }
    for (; i < i1; ++i) {
        int s = csr[i];
        float e = el[s * NH + h];
        ushort4 hv = *reinterpret_cast<const ushort4*>(&Hb[(size_t)s * DIM + c4]);
        ax0 = fmaf(b2f(hv.x), e, ax0); ay0 = fmaf(b2f(hv.y), e, ay0);
        az0 = fmaf(b2f(hv.z), e, az0); aw0 = fmaf(b2f(hv.w), e, aw0);
        den0 += e;
    }
    float ax = ax0 + ax1, ay = ay0 + ay1, az = az0 + az1, aw = aw0 + aw1;
    float den = den0 + den1;
    float erv = er[wid * NH + h];
    float inv = erv / fmaf(den, erv, 1e-12f);
    ushort4 r = { f2b(ax * inv), f2b(ay * inv), f2b(az * inv), f2b(aw * inv) };
    *reinterpret_cast<ushort4*>(&outb[(size_t)wid * DIM + c4]) = r;
}

// ------------------------------------------------------- BatchNorm stats
__global__ __launch_bounds__(256) void bn_partial_bf16(
    const unsigned short* __restrict__ H, float* __restrict__ sums)
{
    const int c = threadIdx.x;
    const int r0 = blockIdx.x * 256;
    const int r1 = min(r0 + 256, NN);
    float s = 0.f, q = 0.f;
    for (int r = r0; r < r1; ++r) {
        float v = b2f(H[(size_t)r * DIM + c]);
        s += v;
        q = fmaf(v, v, q);
    }
    atomicAdd(&sums[c], s);
    atomicAdd(&sums[DIM + c], q);
}

// ---------------------------------------------------------------------------
extern "C" void kernel_launch(void* const* d_in, const int* in_sizes, int n_in,
                              void* d_out, int out_size, void* d_ws, size_t ws_size,
                              hipStream_t stream)
{
    const float* x   = (const float*)d_in[0];
    const int*   ei  = (const int*)  d_in[1];
    const float* W1  = (const float*)d_in[2];
    const float* b1  = (const float*)d_in[3];
    const float* al1 = (const float*)d_in[4];
    const float* ar1 = (const float*)d_in[5];
    const float* g1  = (const float*)d_in[6];
    const float* be1 = (const float*)d_in[7];
    const float* W2  = (const float*)d_in[8];
    const float* b2  = (const float*)d_in[9];
    const float* al2 = (const float*)d_in[10];
    const float* ar2 = (const float*)d_in[11];
    const float* g2  = (const float*)d_in[12];
    const float* be2 = (const float*)d_in[13];
    const float* Wh  = (const float*)d_in[14];
    const float* bh  = (const float*)d_in[15];
    float* out = (float*)d_out;

    float* ws     = (float*)d_ws;
    float* el     = ws;                      // NN*NH
    float* er     = el + NN * NH;            // NN*NH
    float* bnsum1 = er + NN * NH;            // 2*DIM  (start of memset region)
    float* bnsum2 = bnsum1 + 2 * DIM;        // 2*DIM
    int*   deg    = (int*)(bnsum2 + 2 * DIM);// NN
    int*   cursor = deg + NN;                // NN     (end of memset region)
    int*   rowoff = cursor + NN;             // NN+1
    int*   bsum   = rowoff + NN + 1;         // 256
    int*   csr    = bsum + 256;              // NE2
    unsigned short* Hb =
        (unsigned short*)((((uintptr_t)(csr + NE2)) + 63) & ~(uintptr_t)63);
    unsigned short* Ab  = Hb  + (size_t)MPAD * 256;  // MPAD*256
    unsigned short* Wt1 = Ab  + (size_t)MPAD * 256;  // 256*256
    unsigned short* Wt2 = Wt1 + 256 * 256;
    unsigned short* Wth = Wt2 + 256 * 256;           // 128*256

    const int gemmBlocks  = MPAD / 64;               // 782 (3.05 blocks/CU)
    const int edgeBlocks  = (NE2 + 255) / 256;       // 3321
    const int nodeBlocks  = (NN * 64 + 255) / 256;   // 12500 (wave per node)
    const int bnpBlocks   = (NN + 255) / 256;        // 196

    // ---------------- weight casts + one merged scratch zero
    cast_wt_all<<<256, 256, 0, stream>>>(W1, W2, Wh, Wt1, Wt2, Wth);
    hipMemsetAsync(bnsum1, 0, (4 * DIM + 2 * NN) * sizeof(float), stream);

    // ---------------- CSR build (same graph both layers)
    deg_count<<<edgeBlocks, 256, 0, stream>>>(ei, deg);
    scan_block_sums<<<NBLK, 256, 0, stream>>>(deg, bsum);
    scan_bsum<<<1, 256, 0, stream>>>(bsum);
    scan_write<<<NBLK, 256, 0, stream>>>(deg, bsum, rowoff);
    csr_fill<<<edgeBlocks, 256, 0, stream>>>(ei, rowoff, cursor, csr);

    // ---------------- layer 1 (GEMM fuses x-cast + score factors)
    gemm_wide<0><<<gemmBlocks, 256, 0, stream>>>(x, nullptr, Wt1, b1,
                                                 nullptr, nullptr, nullptr,
                                                 al1, ar1, el, er, Hb);
    gat_aggregate_csr_bf16<<<nodeBlocks, 256, 0, stream>>>(csr, rowoff, Hb, el, er, Ab);
    bn_partial_bf16<<<bnpBlocks, 256, 0, stream>>>(Ab, bnsum1);

    // ---------------- layer 2 (GEMM fuses BN1+ReLU + score factors)
    gemm_wide<1><<<gemmBlocks, 256, 0, stream>>>(nullptr, Ab, Wt2, b2,
                                                 bnsum1, g1, be1,
                                                 al2, ar2, el, er, Hb);
    gat_aggregate_csr_bf16<<<nodeBlocks, 256, 0, stream>>>(csr, rowoff, Hb, el, er, Ab);
    bn_partial_bf16<<<bnpBlocks, 256, 0, stream>>>(Ab, bnsum2);

    // ---------------- classification head (fuses BN2+ReLU)
    gemm_head<<<gemmBlocks, 256, 0, stream>>>(Ab, Wth, bh, bnsum2, g2, be2, out);
}

// Round 14
// 471.199 us; speedup vs baseline: 1.0496x; 1.0496x over previous
//
#include <hip/hip_runtime.h>
#include <hip/hip_bf16.h>
#include <math.h>

#define NN   50000
#define NE   400000
#define NE2  (2*NE + NN)      // 850000 edges after symmetrize + self loops
#define DIM  256
#define NH   8
#define NM   (NN*DIM)         // 12,800,000 elements per activation buffer
#define NBLK 196              // ceil(NN/256) blocks for scan
#define MPAD 50048            // 391*128, padded row count for bf16 activations

typedef __attribute__((ext_vector_type(8))) short bf16x8;
typedef __attribute__((ext_vector_type(8))) unsigned short u16x8;
typedef __attribute__((ext_vector_type(4))) float f32x4;

#define GLOAD16(g, l) __builtin_amdgcn_global_load_lds( \
    (const __attribute__((address_space(1))) void*)(g), \
    (__attribute__((address_space(3))) void*)(l), 16, 0, 0)

__device__ __forceinline__ float b2f(unsigned short u) {
    unsigned int i = ((unsigned int)u) << 16;
    float f; __builtin_memcpy(&f, &i, 4); return f;
}
__device__ __forceinline__ unsigned short f2b(float f) {
    __hip_bfloat16 h = __float2bfloat16(f);
    unsigned short u; __builtin_memcpy(&u, &h, 2); return u;
}

// --------------------------------------------- fused wide bf16 MFMA GEMM
// Cb[MPAD,256] = T(A)[MPAD,256] @ Bt[256,256]^T + bias, bf16 out, unguarded.
// MODE 0: A = fp32 x (raw in LDS), T = bf16 cast at fragment read.
// MODE 1: A = bf16 raw aggregate (raw in LDS), T = BN+ReLU at fragment read.
// A and B both staged via global_load_lds (fast path); transform applied
// between ds_read and MFMA. 512 thr = 8 waves (2 row x 4 col), 128x256 tile.
template<int MODE>
__global__ __launch_bounds__(512) void gemm_wide(
    const float* __restrict__ Af, const unsigned short* __restrict__ Ab16,
    const unsigned short* __restrict__ Bt, const float* __restrict__ bias,
    const float* __restrict__ sums, const float* __restrict__ g,
    const float* __restrict__ be, unsigned short* __restrict__ Cb)
{
    __shared__ char  ldsA[(MODE == 0) ? 16384 : 8192];  // raw A tile
    __shared__ short ldsB[4][256][8];                   // 16 KiB
    __shared__ float scL[256], shL[256];
    const int tid  = threadIdx.x;
    const int wave = tid >> 6, lane = tid & 63;
    const int wr = wave >> 2, wc = wave & 3;
    const int l15 = lane & 15, lk = lane >> 4;
    const int row0 = blockIdx.x * 128;

    if (MODE == 1) {
        if (tid < 256) {
            float mean = sums[tid] * (1.f / NN);
            float var  = sums[256 + tid] * (1.f / NN) - mean * mean;
            float s    = g[tid] * rsqrtf(var + 1e-5f);
            scL[tid] = s;
            shL[tid] = be[tid] - mean * s;
        }
        __syncthreads();
    }

    f32x4 acc[4][4] = {};
    for (int t = 0; t < 8; ++t) {
        const int k0 = t * 32;
        if (t) __syncthreads();                       // prior reads done
        // ---- A stage: raw global->LDS (linear dest = seg*16)
        if (MODE == 0) {
            #pragma unroll
            for (int c = 0; c < 2; ++c) {
                int seg = c * 512 + tid;              // 0..1023
                int pp = seg >> 7, r = seg & 127;
                int rowg = min(row0 + r, NN - 1);     // clamp: x has NN rows
                GLOAD16(Af + (size_t)rowg * 256 + k0 + pp * 4,
                        ldsA + (size_t)seg * 16);
            }
        } else {
            int ch = tid >> 7, r = tid & 127;         // 512 segs of 16B
            GLOAD16(Ab16 + (size_t)(row0 + r) * 256 + k0 + ch * 8,
                    ldsA + (size_t)tid * 16);
        }
        // ---- B stage
        #pragma unroll
        for (int c = 0; c < 2; ++c) {
            int seg = c * 512 + tid;                  // 0..1023
            int bch = seg >> 8, br = seg & 255;
            GLOAD16(Bt + (size_t)br * 256 + k0 + bch * 8, &ldsB[bch][br][0]);
        }
        __syncthreads();                              // drains vmcnt+lgkm
        // ---- fragments (+ transform) + MFMA
        bf16x8 af[4], bf[4];
        #pragma unroll
        for (int m = 0; m < 4; ++m) {
            int r = wr * 64 + m * 16 + l15;
            if (MODE == 0) {
                float4 v0 = *reinterpret_cast<const float4*>(
                    ldsA + (size_t)(2 * lk) * 2048 + (size_t)r * 16);
                float4 v1 = *reinterpret_cast<const float4*>(
                    ldsA + (size_t)(2 * lk + 1) * 2048 + (size_t)r * 16);
                bf16x8 o;
                o[0]=(short)f2b(v0.x); o[1]=(short)f2b(v0.y);
                o[2]=(short)f2b(v0.z); o[3]=(short)f2b(v0.w);
                o[4]=(short)f2b(v1.x); o[5]=(short)f2b(v1.y);
                o[6]=(short)f2b(v1.z); o[7]=(short)f2b(v1.w);
                af[m] = o;
            } else {
                u16x8 rw = *reinterpret_cast<const u16x8*>(
                    ldsA + (size_t)lk * 2048 + (size_t)r * 16);
                int kc = k0 + lk * 8;
                float4 s0 = *reinterpret_cast<const float4*>(&scL[kc]);
                float4 s1 = *reinterpret_cast<const float4*>(&scL[kc + 4]);
                float4 h0 = *reinterpret_cast<const float4*>(&shL[kc]);
                float4 h1 = *reinterpret_cast<const float4*>(&shL[kc + 4]);
                bf16x8 o;
                o[0]=(short)f2b(fmaxf(0.f, fmaf(b2f(rw[0]), s0.x, h0.x)));
                o[1]=(short)f2b(fmaxf(0.f, fmaf(b2f(rw[1]), s0.y, h0.y)));
                o[2]=(short)f2b(fmaxf(0.f, fmaf(b2f(rw[2]), s0.z, h0.z)));
                o[3]=(short)f2b(fmaxf(0.f, fmaf(b2f(rw[3]), s0.w, h0.w)));
                o[4]=(short)f2b(fmaxf(0.f, fmaf(b2f(rw[4]), s1.x, h1.x)));
                o[5]=(short)f2b(fmaxf(0.f, fmaf(b2f(rw[5]), s1.y, h1.y)));
                o[6]=(short)f2b(fmaxf(0.f, fmaf(b2f(rw[6]), s1.z, h1.z)));
                o[7]=(short)f2b(fmaxf(0.f, fmaf(b2f(rw[7]), s1.w, h1.w)));
                af[m] = o;
            }
        }
        #pragma unroll
        for (int n = 0; n < 4; ++n)
            bf[n] = *reinterpret_cast<const bf16x8*>(&ldsB[lk][wc*64 + n*16 + l15][0]);
        #pragma unroll
        for (int m = 0; m < 4; ++m)
            #pragma unroll
            for (int n = 0; n < 4; ++n)
                acc[m][n] = __builtin_amdgcn_mfma_f32_16x16x32_bf16(af[m], bf[n], acc[m][n], 0, 0, 0);
    }
    #pragma unroll
    for (int m = 0; m < 4; ++m) {
        #pragma unroll
        for (int n = 0; n < 4; ++n) {
            int col = wc*64 + n*16 + l15;
            float bv = bias[col];
            #pragma unroll
            for (int q = 0; q < 4; ++q) {
                int row = row0 + wr*64 + m*16 + lk*4 + q;
                Cb[(size_t)row * 256 + col] = f2b(acc[m][n][q] + bv);
            }
        }
    }
}

// ------------------------------------------- head GEMM: BN+ReLU at frag read
// C[NN,128] = BN2(A)[.,256] @ Wth[128,256]^T + bias, fp32 out, guarded.
__global__ __launch_bounds__(256) void gemm_head(
    const unsigned short* __restrict__ Ab16, const unsigned short* __restrict__ Bt,
    const float* __restrict__ bias, const float* __restrict__ sums,
    const float* __restrict__ g, const float* __restrict__ be,
    float* __restrict__ C)
{
    __shared__ short ldsA[4][128][8];   // raw bf16 A tile, 8 KiB
    __shared__ short ldsB[4][128][8];
    __shared__ float scL[256], shL[256];
    const int tid  = threadIdx.x;
    const int wave = tid >> 6, lane = tid & 63;
    const int wr = wave >> 1, wc = wave & 1;
    const int l15 = lane & 15, lk = lane >> 4;
    const int row0 = blockIdx.x * 128;

    {
        float mean = sums[tid] * (1.f / NN);
        float var  = sums[256 + tid] * (1.f / NN) - mean * mean;
        float s    = g[tid] * rsqrtf(var + 1e-5f);
        scL[tid] = s;
        shL[tid] = be[tid] - mean * s;
    }
    __syncthreads();

    f32x4 acc[4][4] = {};
    for (int t = 0; t < 8; ++t) {
        const int k0 = t * 32;
        if (t) __syncthreads();
        #pragma unroll
        for (int c = 0; c < 2; ++c) {
            int seg = c * 256 + tid;        // 0..511
            int ch = seg >> 7, r = seg & 127;
            GLOAD16(Ab16 + (size_t)(row0 + r) * 256 + k0 + ch * 8, &ldsA[ch][r][0]);
            GLOAD16(Bt   + (size_t)r * 256 + k0 + ch * 8, &ldsB[ch][r][0]);
        }
        __syncthreads();
        bf16x8 af[4], bf[4];
        #pragma unroll
        for (int m = 0; m < 4; ++m) {
            int r = wr * 64 + m * 16 + l15;
            u16x8 rw = *reinterpret_cast<const u16x8*>(&ldsA[lk][r][0]);
            int kc = k0 + lk * 8;
            float4 s0 = *reinterpret_cast<const float4*>(&scL[kc]);
            float4 s1 = *reinterpret_cast<const float4*>(&scL[kc + 4]);
            float4 h0 = *reinterpret_cast<const float4*>(&shL[kc]);
            float4 h1 = *reinterpret_cast<const float4*>(&shL[kc + 4]);
            bf16x8 o;
            o[0]=(short)f2b(fmaxf(0.f, fmaf(b2f(rw[0]), s0.x, h0.x)));
            o[1]=(short)f2b(fmaxf(0.f, fmaf(b2f(rw[1]), s0.y, h0.y)));
            o[2]=(short)f2b(fmaxf(0.f, fmaf(b2f(rw[2]), s0.z, h0.z)));
            o[3]=(short)f2b(fmaxf(0.f, fmaf(b2f(rw[3]), s0.w, h0.w)));
            o[4]=(short)f2b(fmaxf(0.f, fmaf(b2f(rw[4]), s1.x, h1.x)));
            o[5]=(short)f2b(fmaxf(0.f, fmaf(b2f(rw[5]), s1.y, h1.y)));
            o[6]=(short)f2b(fmaxf(0.f, fmaf(b2f(rw[6]), s1.z, h1.z)));
            o[7]=(short)f2b(fmaxf(0.f, fmaf(b2f(rw[7]), s1.w, h1.w)));
            af[m] = o;
        }
        #pragma unroll
        for (int n = 0; n < 4; ++n)
            bf[n] = *reinterpret_cast<const bf16x8*>(&ldsB[lk][wc*64 + n*16 + l15][0]);
        #pragma unroll
        for (int m = 0; m < 4; ++m)
            #pragma unroll
            for (int n = 0; n < 4; ++n)
                acc[m][n] = __builtin_amdgcn_mfma_f32_16x16x32_bf16(af[m], bf[n], acc[m][n], 0, 0, 0);
    }
    #pragma unroll
    for (int m = 0; m < 4; ++m) {
        #pragma unroll
        for (int n = 0; n < 4; ++n) {
            int col = wc*64 + n*16 + l15;
            float bv = bias[col];
            #pragma unroll
            for (int q = 0; q < 4; ++q) {
                int row = row0 + wr*64 + m*16 + lk*4 + q;
                if (row < NN) C[(size_t)row * 128 + col] = acc[m][n][q] + bv;
            }
        }
    }
}

// --------------------------------------------------------------- weight cast
__global__ __launch_bounds__(256) void cast_wt_all(
    const float* __restrict__ W1, const float* __restrict__ W2,
    const float* __restrict__ Wh, unsigned short* __restrict__ Wt1,
    unsigned short* __restrict__ Wt2, unsigned short* __restrict__ Wth)
{
    int i = blockIdx.x * 256 + threadIdx.x;   // 0..65535
    {
        int k = i >> 8, n = i & 255;          // W[256,256]
        Wt1[n * 256 + k] = f2b(W1[i]);
        Wt2[n * 256 + k] = f2b(W2[i]);
    }
    if (i < 256 * 128) {
        int k = i >> 7, n = i & 127;          // Wh[256,128]
        Wth[n * 256 + k] = f2b(Wh[i]);
    }
}

// ------------------------------------------------- per-node attention factors
// wave per node; writes el = exp(<H[n],a_l>), er = exp(<H[n],a_r>) per head
__global__ __launch_bounds__(256) void gat_scores_bf16(
    const unsigned short* __restrict__ Hb, const float* __restrict__ a_l,
    const float* __restrict__ a_r, float* __restrict__ el,
    float* __restrict__ er)
{
    const int wave = threadIdx.x >> 6;
    const int lane = threadIdx.x & 63;
    const int n = blockIdx.x * 4 + wave;
    if (n >= NN) return;
    const int c = lane * 4;
    const int h = lane >> 3;
    ushort4 hv = *reinterpret_cast<const ushort4*>(&Hb[(size_t)n * DIM + c]);
    float4 al4 = *reinterpret_cast<const float4*>(&a_l[c]);
    float4 ar4 = *reinterpret_cast<const float4*>(&a_r[c]);
    float x0 = b2f(hv.x), x1 = b2f(hv.y), x2 = b2f(hv.z), x3 = b2f(hv.w);
    float pl = x0*al4.x + x1*al4.y + x2*al4.z + x3*al4.w;
    float pr = x0*ar4.x + x1*ar4.y + x2*ar4.z + x3*ar4.w;
    #pragma unroll
    for (int o = 1; o < 8; o <<= 1) {
        pl += __shfl_xor(pl, o, 64);
        pr += __shfl_xor(pr, o, 64);
    }
    if ((lane & 7) == 0) {
        el[n * NH + h] = expf(pl);
        er[n * NH + h] = expf(pr);
    }
}

// edge decode: e2 in [0,NE): (ei0,ei1); [NE,2NE): reversed; [2NE,NE2): self
__device__ __forceinline__ void edge_sd(const int* __restrict__ ei, int e2,
                                        int& s, int& d)
{
    if (e2 < NE)          { s = ei[e2];      d = ei[e2 + NE]; }
    else if (e2 < 2 * NE) { s = ei[e2];      d = ei[e2 - NE]; }
    else                  { s = e2 - 2 * NE; d = s; }
}

// --------------------------------------------------------------- CSR build
__global__ __launch_bounds__(256) void deg_count(const int* __restrict__ ei,
                                                 int* __restrict__ deg)
{
    int e2 = blockIdx.x * 256 + threadIdx.x;
    if (e2 >= NE2) return;
    int s, d;
    edge_sd(ei, e2, s, d);
    atomicAdd(&deg[d], 1);
}

__global__ __launch_bounds__(256) void scan_block_sums(
    const int* __restrict__ deg, int* __restrict__ bsum)
{
    __shared__ int tmp[256];
    const int t = threadIdx.x;
    int i = blockIdx.x * 256 + t;
    tmp[t] = (i < NN) ? deg[i] : 0;
    __syncthreads();
    #pragma unroll
    for (int o = 128; o > 0; o >>= 1) {
        if (t < o) tmp[t] += tmp[t + o];
        __syncthreads();
    }
    if (t == 0) bsum[blockIdx.x] = tmp[0];
}

__global__ void scan_bsum(int* __restrict__ bsum)   // 1 block, 256 threads
{
    __shared__ int tmp[256];
    const int t = threadIdx.x;
    int v = (t < NBLK) ? bsum[t] : 0;
    tmp[t] = v;
    __syncthreads();
    #pragma unroll
    for (int o = 1; o < 256; o <<= 1) {
        int x = (t >= o) ? tmp[t - o] : 0;
        __syncthreads();
        tmp[t] += x;
        __syncthreads();
    }
    bsum[t] = tmp[t] - v;   // exclusive prefix of block sums
}

__global__ __launch_bounds__(256) void scan_write(
    const int* __restrict__ deg, const int* __restrict__ bsum,
    int* __restrict__ rowoff)
{
    __shared__ int tmp[256];
    const int t = threadIdx.x;
    int i = blockIdx.x * 256 + t;
    int v = (i < NN) ? deg[i] : 0;
    tmp[t] = v;
    __syncthreads();
    #pragma unroll
    for (int o = 1; o < 256; o <<= 1) {
        int x = (t >= o) ? tmp[t - o] : 0;
        __syncthreads();
        tmp[t] += x;
        __syncthreads();
    }
    if (i <= NN) rowoff[i] = bsum[blockIdx.x] + tmp[t] - v;
}

__global__ __launch_bounds__(256) void csr_fill(
    const int* __restrict__ ei, const int* __restrict__ rowoff,
    int* __restrict__ cursor, int* __restrict__ csr)
{
    int e2 = blockIdx.x * 256 + threadIdx.x;
    if (e2 >= NE2) return;
    int s, d;
    edge_sd(ei, e2, s, d);
    int pos = atomicAdd(&cursor[d], 1);
    csr[rowoff[d] + pos] = s;
}

// ------------------------- fused softmax + aggregation, no atomics, no expf
// out[d] = er[d]*sum(el[s]*H[s]) / (er[d]*sum(el[s]) + eps); unroll x4 (best).
__global__ __launch_bounds__(256) void gat_aggregate_csr_bf16(
    const int* __restrict__ csr, const int* __restrict__ rowoff,
    const unsigned short* __restrict__ Hb, const float* __restrict__ el,
    const float* __restrict__ er, unsigned short* __restrict__ outb)
{
    const int wid  = (blockIdx.x * 256 + threadIdx.x) >> 6;   // node id
    const int lane = threadIdx.x & 63;
    if (wid >= NN) return;
    const int h = lane >> 3;
    const int i0 = rowoff[wid], i1 = rowoff[wid + 1];
    const int c4 = lane * 4;

    float ax0 = 0.f, ay0 = 0.f, az0 = 0.f, aw0 = 0.f, den0 = 0.f;
    float ax1 = 0.f, ay1 = 0.f, az1 = 0.f, aw1 = 0.f, den1 = 0.f;

    int i = i0;
    for (; i + 4 <= i1; i += 4) {
        int s0 = csr[i + 0], s1 = csr[i + 1], s2 = csr[i + 2], s3 = csr[i + 3];
        float e0 = el[s0 * NH + h], e1 = el[s1 * NH + h];
        float e2 = el[s2 * NH + h], e3 = el[s3 * NH + h];
        ushort4 h0 = *reinterpret_cast<const ushort4*>(&Hb[(size_t)s0 * DIM + c4]);
        ushort4 h1 = *reinterpret_cast<const ushort4*>(&Hb[(size_t)s1 * DIM + c4]);
        ushort4 h2 = *reinterpret_cast<const ushort4*>(&Hb[(size_t)s2 * DIM + c4]);
        ushort4 h3 = *reinterpret_cast<const ushort4*>(&Hb[(size_t)s3 * DIM + c4]);
        ax0 = fmaf(b2f(h0.x), e0, ax0); ay0 = fmaf(b2f(h0.y), e0, ay0);
        az0 = fmaf(b2f(h0.z), e0, az0); aw0 = fmaf(b2f(h0.w), e0, aw0);
        den0 += e0;
        ax1 = fmaf(b2f(h1.x), e1, ax1); ay1 = fmaf(b2f(h1.y), e1, ay1);
        az1 = fmaf(b2f(h1.z), e1, az1); aw1 = fmaf(b2f(h1.w), e1, aw1);
        den1 += e1;
        ax0 = fmaf(b2f(h2.x), e2, ax0); ay0 = fmaf(b2f(h2.y), e2, ay0);
        az0 = fmaf(b2f(h2.z), e2, az0); aw0 = fmaf(b2f(h2.w), e2, aw0);
        den0 += e2;
        ax1 = fmaf(b2f(h3.x), e3, ax1); ay1 = fmaf(b2f(h3.y), e3, ay1);
        az1 = fmaf(b2f(h3.z), e3, az1); aw1 = fmaf(b2f(h3.w), e3, aw1);
        den1 += e3;
    }
    for (; i < i1; ++i) {
        int s = csr[i];
        float e = el[s * NH + h];
        ushort4 hv = *reinterpret_cast<const ushort4*>(&Hb[(size_t)s * DIM + c4]);
        ax0 = fmaf(b2f(hv.x), e, ax0); ay0 = fmaf(b2f(hv.y), e, ay0);
        az0 = fmaf(b2f(hv.z), e, az0); aw0 = fmaf(b2f(hv.w), e, aw0);
        den0 += e;
    }
    float ax = ax0 + ax1, ay = ay0 + ay1, az = az0 + az1, aw = aw0 + aw1;
    float den = den0 + den1;
    float erv = er[wid * NH + h];
    float inv = erv / fmaf(den, erv, 1e-12f);
    ushort4 r = { f2b(ax * inv), f2b(ay * inv), f2b(az * inv), f2b(aw * inv) };
    *reinterpret_cast<ushort4*>(&outb[(size_t)wid * DIM + c4]) = r;
}

// ------------------------------------------------------- BatchNorm stats
__global__ __launch_bounds__(256) void bn_partial_bf16(
    const unsigned short* __restrict__ H, float* __restrict__ sums)
{
    const int c = threadIdx.x;
    const int r0 = blockIdx.x * 256;
    const int r1 = min(r0 + 256, NN);
    float s = 0.f, q = 0.f;
    for (int r = r0; r < r1; ++r) {
        float v = b2f(H[(size_t)r * DIM + c]);
        s += v;
        q = fmaf(v, v, q);
    }
    atomicAdd(&sums[c], s);
    atomicAdd(&sums[DIM + c], q);
}

// ---------------------------------------------------------------------------
extern "C" void kernel_launch(void* const* d_in, const int* in_sizes, int n_in,
                              void* d_out, int out_size, void* d_ws, size_t ws_size,
                              hipStream_t stream)
{
    const float* x   = (const float*)d_in[0];
    const int*   ei  = (const int*)  d_in[1];
    const float* W1  = (const float*)d_in[2];
    const float* b1  = (const float*)d_in[3];
    const float* al1 = (const float*)d_in[4];
    const float* ar1 = (const float*)d_in[5];
    const float* g1  = (const float*)d_in[6];
    const float* be1 = (const float*)d_in[7];
    const float* W2  = (const float*)d_in[8];
    const float* b2  = (const float*)d_in[9];
    const float* al2 = (const float*)d_in[10];
    const float* ar2 = (const float*)d_in[11];
    const float* g2  = (const float*)d_in[12];
    const float* be2 = (const float*)d_in[13];
    const float* Wh  = (const float*)d_in[14];
    const float* bh  = (const float*)d_in[15];
    float* out = (float*)d_out;

    float* ws     = (float*)d_ws;
    float* el     = ws;                      // NN*NH
    float* er     = el + NN * NH;            // NN*NH
    float* bnsum1 = er + NN * NH;            // 2*DIM  (start of memset region)
    float* bnsum2 = bnsum1 + 2 * DIM;        // 2*DIM
    int*   deg    = (int*)(bnsum2 + 2 * DIM);// NN
    int*   cursor = deg + NN;                // NN     (end of memset region)
    int*   rowoff = cursor + NN;             // NN+1
    int*   bsum   = rowoff + NN + 1;         // 256
    int*   csr    = bsum + 256;              // NE2
    unsigned short* Hb =
        (unsigned short*)((((uintptr_t)(csr + NE2)) + 63) & ~(uintptr_t)63);
    unsigned short* Ab  = Hb  + (size_t)MPAD * 256;  // MPAD*256
    unsigned short* Wt1 = Ab  + (size_t)MPAD * 256;  // 256*256
    unsigned short* Wt2 = Wt1 + 256 * 256;
    unsigned short* Wth = Wt2 + 256 * 256;           // 128*256

    const int gemmBlocks  = MPAD / 128;              // 391
    const int edgeBlocks  = (NE2 + 255) / 256;       // 3321
    const int nodeBlocks  = (NN * 64 + 255) / 256;   // 12500 (wave per node)
    const int bnpBlocks   = (NN + 255) / 256;        // 196

    // ---------------- weight casts + one merged scratch zero
    cast_wt_all<<<256, 256, 0, stream>>>(W1, W2, Wh, Wt1, Wt2, Wth);
    hipMemsetAsync(bnsum1, 0, (4 * DIM + 2 * NN) * sizeof(float), stream);

    // ---------------- CSR build (same graph both layers)
    deg_count<<<edgeBlocks, 256, 0, stream>>>(ei, deg);
    scan_block_sums<<<NBLK, 256, 0, stream>>>(deg, bsum);
    scan_bsum<<<1, 256, 0, stream>>>(bsum);
    scan_write<<<NBLK, 256, 0, stream>>>(deg, bsum, rowoff);
    csr_fill<<<edgeBlocks, 256, 0, stream>>>(ei, rowoff, cursor, csr);

    // ---------------- layer 1 (GEMM fuses x cast at fragment read)
    gemm_wide<0><<<gemmBlocks, 512, 0, stream>>>(x, nullptr, Wt1, b1,
                                                 nullptr, nullptr, nullptr, Hb);
    gat_scores_bf16<<<nodeBlocks, 256, 0, stream>>>(Hb, al1, ar1, el, er);
    gat_aggregate_csr_bf16<<<nodeBlocks, 256, 0, stream>>>(csr, rowoff, Hb, el, er, Ab);
    bn_partial_bf16<<<bnpBlocks, 256, 0, stream>>>(Ab, bnsum1);

    // ---------------- layer 2 (GEMM fuses BN1+ReLU at fragment read)
    gemm_wide<1><<<gemmBlocks, 512, 0, stream>>>(nullptr, Ab, Wt2, b2,
                                                 bnsum1, g1, be1, Hb);
    gat_scores_bf16<<<nodeBlocks, 256, 0, stream>>>(Hb, al2, ar2, el, er);
    gat_aggregate_csr_bf16<<<nodeBlocks, 256, 0, stream>>>(csr, rowoff, Hb, el, er, Ab);
    bn_partial_bf16<<<bnpBlocks, 256, 0, stream>>>(Ab, bnsum2);

    // ---------------- classification head (fuses BN2+ReLU)
    gemm_head<<<gemmBlocks, 256, 0, stream>>>(Ab, Wth, bh, bnsum2, g2, be2, out);
}